// Round 2
// baseline (307.124 us; speedup 1.0000x reference)
//
#include <hip/hip_runtime.h>
#include <math.h>

typedef unsigned short u16;
typedef unsigned int   u32;
typedef __attribute__((ext_vector_type(8))) unsigned short bf16x8;
typedef __attribute__((ext_vector_type(4))) float f32x4;

// ---- constants (B,T,D,N,S,H from reference) ----
#define BT   4096      // B*T
#define D    2048
#define NC   8         // n_concepts
#define NCOL 128       // 64 selector cols + 64 lora_update cols
#define TM   128
#define KC   32

__device__ __forceinline__ float bf2f(u16 v) {
    u32 u = ((u32)v) << 16;
    float f; __builtin_memcpy(&f, &u, 4); return f;
}
__device__ __forceinline__ u16 f2bf(float f) {
    u32 u; __builtin_memcpy(&u, &f, 4);
    u32 lsb = (u >> 16) & 1;
    u += 0x7fffu + lsb;            // round-to-nearest-even
    return (u16)(u >> 16);
}

// ---- dtype-polymorphic load/store: DT=0 bf16, DT=1 fp32 ----
template<int DT> struct IO;
template<> struct IO<0> {
    static __device__ __forceinline__ float ld1(const void* p, size_t i) {
        return bf2f(((const u16*)p)[i]);
    }
    static __device__ __forceinline__ void ld8(const void* p, size_t i, float* o) {
        bf16x8 v = *(const bf16x8*)((const u16*)p + i);
#pragma unroll
        for (int k = 0; k < 8; k++) o[k] = bf2f(v[k]);
    }
    static __device__ __forceinline__ void st8(void* p, size_t i, const float* v) {
        bf16x8 o;
#pragma unroll
        for (int k = 0; k < 8; k++) o[k] = f2bf(v[k]);
        *(bf16x8*)((u16*)p + i) = o;
    }
};
template<> struct IO<1> {
    static __device__ __forceinline__ float ld1(const void* p, size_t i) {
        return ((const float*)p)[i];
    }
    static __device__ __forceinline__ void ld8(const void* p, size_t i, float* o) {
        f32x4 a = *(const f32x4*)((const float*)p + i);
        f32x4 b = *(const f32x4*)((const float*)p + i + 4);
#pragma unroll
        for (int k = 0; k < 4; k++) { o[k] = a[k]; o[4 + k] = b[k]; }
    }
    static __device__ __forceinline__ void st8(void* p, size_t i, const float* v) {
        f32x4 a, b;
#pragma unroll
        for (int k = 0; k < 4; k++) { a[k] = v[k]; b[k] = v[4 + k]; }
        *(f32x4*)((float*)p + i) = a;
        *(f32x4*)((float*)p + i + 4) = b;
    }
};

// ---------------------------------------------------------------------------
// Detector: interpret first 4096 u16 of x as bf16. True-bf16 N(0,1) data has
// |v| < ~6; fp32 bit patterns read as bf16 give |v|>1e4 or NaN w.p. ~1.
// flag=1 -> inputs are fp32.
// ---------------------------------------------------------------------------
__global__ void k_detect(const u16* __restrict__ x, int* __restrict__ flag) {
    __shared__ int s;
    int t = threadIdx.x;
    if (t == 0) s = 0;
    __syncthreads();
    bool bad = false;
    for (int i = t; i < 4096; i += 256) {
        float v = bf2f(x[i]);
        if (!(fabsf(v) < 1e4f)) bad = true;   // catches NaN too
    }
    if (bad) s = 1;
    __syncthreads();
    if (t == 0) *flag = s;
}

// ---------------------------------------------------------------------------
// Wt fp32 [D][128]: cols 0..63 = select_weight (n*8+s), 64..127 = lora_update
// ---------------------------------------------------------------------------
template<int DT>
__device__ __forceinline__ void wt_body(const void* W, const void* U, float* Wt) {
    int idx = blockIdx.x * 256 + threadIdx.x;   // 2048*128 total
    int d = idx >> 7, j = idx & 127;
    float v;
    if (j < 64) v = IO<DT>::ld1(W, ((size_t)(j >> 3) * D + d) * 8 + (j & 7));
    else        v = IO<DT>::ld1(U, ((size_t)((j - 64) >> 3) * D + d) * 8 + (j & 7));
    Wt[d * NCOL + j] = v;
}
__global__ void k_wt(const void* W, const void* U, float* Wt, const int* flag) {
    if (*flag) wt_body<1>(W, U, Wt); else wt_body<0>(W, U, Wt);
}

// ---------------------------------------------------------------------------
// Per-concept constants: off[n][s]=W·mu, mu2[n]=|mu|^2, ub[n][h]=upd·debias
// ---------------------------------------------------------------------------
template<int DT>
__device__ __forceinline__ void consts_body(const void* W, const void* mu,
                                            const void* upd, const void* deb,
                                            float* gOff, float* gMu2, float* gUb) {
    int n = blockIdx.x, t = threadIdx.x;
    float o[8] = {}, u[8] = {};
    float m2 = 0.f;
    for (int d = t; d < D; d += 256) {
        float mud = IO<DT>::ld1(mu,  (size_t)n * D + d);
        float dbd = IO<DT>::ld1(deb, (size_t)n * D + d);
        m2 += mud * mud;
        float wv[8], uv[8];
        IO<DT>::ld8(W,   ((size_t)n * D + d) * 8, wv);
        IO<DT>::ld8(upd, ((size_t)n * D + d) * 8, uv);
#pragma unroll
        for (int s = 0; s < 8; s++) {
            o[s] += wv[s] * mud;
            u[s] += uv[s] * dbd;
        }
    }
#pragma unroll
    for (int i = 1; i < 64; i <<= 1) {
        m2 += __shfl_xor(m2, i, 64);
#pragma unroll
        for (int s = 0; s < 8; s++) {
            o[s] += __shfl_xor(o[s], i, 64);
            u[s] += __shfl_xor(u[s], i, 64);
        }
    }
    __shared__ float red[4][17];
    int wave = t >> 6, lane = t & 63;
    if (lane == 0) {
        red[wave][0] = m2;
#pragma unroll
        for (int s = 0; s < 8; s++) { red[wave][1 + s] = o[s]; red[wave][9 + s] = u[s]; }
    }
    __syncthreads();
    if (t == 0) {
        float acc[17];
#pragma unroll
        for (int i = 0; i < 17; i++)
            acc[i] = red[0][i] + red[1][i] + red[2][i] + red[3][i];
        gMu2[n] = acc[0];
#pragma unroll
        for (int s = 0; s < 8; s++) { gOff[n * 8 + s] = acc[1 + s]; gUb[n * 8 + s] = acc[9 + s]; }
    }
}
__global__ void k_consts(const void* W, const void* mu, const void* upd, const void* deb,
                         float* gOff, float* gMu2, float* gUb, const int* flag) {
    if (*flag) consts_body<1>(W, mu, upd, deb, gOff, gMu2, gUb);
    else       consts_body<0>(W, mu, upd, deb, gOff, gMu2, gUb);
}

// ---------------------------------------------------------------------------
// GEMM: P[4096][128] += X[4096][2048] * Wt[2048][128], K split 8-way (grid.y)
// ---------------------------------------------------------------------------
template<int DT>
__device__ __forceinline__ void gemm_body(const void* X, const float* __restrict__ Wt,
                                          float* __restrict__ P) {
    __shared__ float Xs[KC * TM];     // [k][token] 16 KB
    __shared__ float Ws[KC * NCOL];   // [k][col]   16 KB
    const int t = threadIdx.x;
    const int tok0 = blockIdx.x * TM;
    const int k0 = blockIdx.y * 256;
    const int gy = t >> 4, gx = t & 15;

    float acc[8][8] = {};

    for (int kc = 0; kc < 256; kc += KC) {
        const int d0 = k0 + kc;
        {
            int row = t >> 2, q = t & 3;
            for (int r = row; r < TM; r += 64) {
                float xv[8];
                IO<DT>::ld8(X, (size_t)(tok0 + r) * D + d0 + q * 8, xv);
#pragma unroll
                for (int i = 0; i < 8; i++)
                    Xs[(q * 8 + i) * TM + r] = xv[i];
            }
        }
        {
            const f32x4* src = (const f32x4*)(Wt + (size_t)d0 * NCOL);
            f32x4* dst = (f32x4*)Ws;
#pragma unroll
            for (int i = 0; i < 4; i++)
                dst[t + i * 256] = src[t + i * 256];
        }
        __syncthreads();

#pragma unroll 4
        for (int k = 0; k < KC; k++) {
            f32x4 xa = *(const f32x4*)&Xs[k * TM + (gy << 3)];
            f32x4 xb = *(const f32x4*)&Xs[k * TM + (gy << 3) + 4];
            f32x4 wa = *(const f32x4*)&Ws[(k << 7) + (gx << 3)];
            f32x4 wb = *(const f32x4*)&Ws[(k << 7) + (gx << 3) + 4];
            float xr[8] = {xa[0], xa[1], xa[2], xa[3], xb[0], xb[1], xb[2], xb[3]};
            float wr[8] = {wa[0], wa[1], wa[2], wa[3], wb[0], wb[1], wb[2], wb[3]};
#pragma unroll
            for (int i = 0; i < 8; i++)
#pragma unroll
                for (int j = 0; j < 8; j++)
                    acc[i][j] = fmaf(xr[i], wr[j], acc[i][j]);
        }
        __syncthreads();
    }

#pragma unroll
    for (int i = 0; i < 8; i++) {
        int tok = tok0 + (gy << 3) + i;
#pragma unroll
        for (int j = 0; j < 8; j++)
            atomicAdd(&P[(size_t)tok * NCOL + (gx << 3) + j], acc[i][j]);
    }
}
__global__ __launch_bounds__(256) void k_gemm(const void* X, const float* Wt,
                                              float* P, const int* flag) {
    if (*flag) gemm_body<1>(X, Wt, P); else gemm_body<0>(X, Wt, P);
}

// ---------------------------------------------------------------------------
// Epilogue: per-token gates -> argmax -> rank-8 reconstruction -> blend
// ---------------------------------------------------------------------------
template<int DT>
__device__ __forceinline__ void final_body(
    const void* X, const float* __restrict__ P,
    const void* MU, const void* CENTER, const void* SLOPE,
    const void* DGN, const void* BIAS,
    const float* __restrict__ OFF, const float* __restrict__ MU2,
    const float* __restrict__ UB, void* OUT) {
    const int tok = blockIdx.x, t = threadIdx.x;
    const int d0 = t * 8;

    __shared__ float red[4][9];
    __shared__ float pc[NCOL];
    __shared__ float bcast[10];

    float xf[8];
    IO<DT>::ld8(X, (size_t)tok * D + d0, xf);

    float vals[9];
    vals[0] = 0.f;
#pragma unroll
    for (int i = 0; i < 8; i++) vals[0] += xf[i] * xf[i];
#pragma unroll
    for (int n = 0; n < 8; n++) {
        float mv[8];
        IO<DT>::ld8(MU, (size_t)n * D + d0, mv);
        float a = 0.f;
#pragma unroll
        for (int i = 0; i < 8; i++) a += xf[i] * mv[i];
        vals[1 + n] = a;
    }
#pragma unroll
    for (int i = 1; i < 64; i <<= 1)
#pragma unroll
        for (int v = 0; v < 9; v++) vals[v] += __shfl_xor(vals[v], i, 64);

    if ((t & 63) == 0)
#pragma unroll
        for (int v = 0; v < 9; v++) red[t >> 6][v] = vals[v];
    if (t < NCOL) pc[t] = P[(size_t)tok * NCOL + t];
    __syncthreads();

    if (t == 0) {
        float sumx2 = red[0][0] + red[1][0] + red[2][0] + red[3][0];
        float best = -1.f; int bi = 0;
        for (int n = 0; n < 8; n++) {
            float mdot = red[0][1 + n] + red[1][1 + n] + red[2][1 + n] + red[3][1 + n];
            float norm2 = sumx2 - 2.f * mdot + MU2[n];
            float sc = 0.f;
#pragma unroll
            for (int s = 0; s < 8; s++) {
                float dg = pc[8 * n + s] - OFF[8 * n + s];
                sc += dg * dg;
            }
            sc /= norm2;
            float z = IO<DT>::ld1(SLOPE, n) * (sc - IO<DT>::ld1(CENTER, n));
            float g = 1.f / (1.f + expf(-z));
            if (g > best) { best = g; bi = n; }   // strict > : first-max == np.argmax
        }
        bcast[0] = best;
        bcast[1] = (float)bi;
#pragma unroll
        for (int h = 0; h < 8; h++)
            bcast[2 + h] = pc[64 + 8 * bi + h] - UB[bi * 8 + h];
    }
    __syncthreads();

    const float sval = bcast[0];
    const int c = (int)bcast[1];
    float mx[8];
#pragma unroll
    for (int h = 0; h < 8; h++) mx[h] = bcast[2 + h];

    float bv[8];
    IO<DT>::ld8(BIAS, (size_t)c * D + d0, bv);
    float ov[8];
#pragma unroll
    for (int i = 0; i < 8; i++) {
        float dv[8];
        IO<DT>::ld8(DGN, ((size_t)c * D + d0) * 8 + i * 8, dv);
        float du = 0.f;
#pragma unroll
        for (int h = 0; h < 8; h++) du += dv[h] * mx[h];
        ov[i] = (1.f - sval) * xf[i] + sval * (bv[i] + du);  // ETA = 1.0
    }
    IO<DT>::st8(OUT, (size_t)tok * D + d0, ov);
}
__global__ __launch_bounds__(256) void k_final(
    const void* X, const float* P, const void* MU, const void* CENTER,
    const void* SLOPE, const void* DGN, const void* BIAS,
    const float* OFF, const float* MU2, const float* UB, void* OUT,
    const int* flag) {
    if (*flag)
        final_body<1>(X, P, MU, CENTER, SLOPE, DGN, BIAS, OFF, MU2, UB, OUT);
    else
        final_body<0>(X, P, MU, CENTER, SLOPE, DGN, BIAS, OFF, MU2, UB, OUT);
}

// ---------------------------------------------------------------------------
extern "C" void kernel_launch(void* const* d_in, const int* in_sizes, int n_in,
                              void* d_out, int out_size, void* d_ws, size_t ws_size,
                              hipStream_t stream) {
    const void* x      = d_in[0];  // [B,T,D]
    const void* selW   = d_in[1];  // [N,D,S]
    const void* mu     = d_in[2];  // [N,D]
    const void* center = d_in[3];  // [N]
    const void* slope  = d_in[4];  // [N]
    const void* upd    = d_in[5];  // [N,D,H]
    const void* dgn    = d_in[6];  // [N,D,H]
    const void* biasW  = d_in[7];  // [N,D]
    const void* debW   = d_in[8];  // [N,D]

    // workspace layout
    char* ws = (char*)d_ws;
    float* P   = (float*)ws;                                   // 2 MB
    float* Wt  = (float*)(ws + (size_t)BT * NCOL * 4);         // 1 MB
    float* off = (float*)(ws + (size_t)BT * NCOL * 4 + (size_t)D * NCOL * 4);
    float* mu2 = off + 64;
    float* ub  = mu2 + 8;
    int*   flag = (int*)(ub + 64);

    k_detect<<<1, 256, 0, stream>>>((const u16*)x, flag);
    hipMemsetAsync(P, 0, (size_t)BT * NCOL * 4, stream);
    k_wt<<<(D * NCOL) / 256, 256, 0, stream>>>(selW, upd, Wt, flag);
    k_consts<<<NC, 256, 0, stream>>>(selW, mu, upd, debW, off, mu2, ub, flag);
    k_gemm<<<dim3(BT / TM, 8), 256, 0, stream>>>(x, Wt, P, flag);
    k_final<<<BT, 256, 0, stream>>>(x, P, mu, center, slope, dgn, biasW,
                                    off, mu2, ub, d_out, flag);
}

// Round 4
// 169.404 us; speedup vs baseline: 1.8130x; 1.8130x over previous
//
#include <hip/hip_runtime.h>
#include <math.h>

typedef unsigned short u16;
typedef unsigned int   u32;
typedef __attribute__((ext_vector_type(8))) unsigned short bf16x8;
typedef __attribute__((ext_vector_type(8))) short sh8;      // MFMA A/B frag (8 bf16)
typedef __attribute__((ext_vector_type(4))) float f32x4;    // MFMA C/D frag

#define BT     4096
#define D      2048
#define NC     8
#define NCOL   144     // 64 selW + 64 upd + 8 mu + 8 zero-pad (9 MFMA col-tiles)
#define KSPLIT 8
#define KR     (D / KSPLIT)   // 256

__device__ __forceinline__ float bf2f(u16 v) {
    u32 u = ((u32)v) << 16;
    float f; __builtin_memcpy(&f, &u, 4); return f;
}
__device__ __forceinline__ u16 f2bf(float f) {
    u32 u; __builtin_memcpy(&u, &f, 4);
    u += 0x7fffu + ((u >> 16) & 1);        // RNE
    return (u16)(u >> 16);
}

// ---- dtype-polymorphic loads: DT=0 bf16 buffers, DT=1 fp32 buffers ----
template<int DT> struct IO;
template<> struct IO<0> {
    static __device__ __forceinline__ float ld1(const void* p, size_t i) {
        return bf2f(((const u16*)p)[i]);
    }
    static __device__ __forceinline__ void ld8(const void* p, size_t i, float* o) {
        bf16x8 v = *(const bf16x8*)((const u16*)p + i);
#pragma unroll
        for (int k = 0; k < 8; k++) o[k] = bf2f(v[k]);
    }
    static __device__ __forceinline__ void st8(void* p, size_t i, const float* v) {
        bf16x8 o;
#pragma unroll
        for (int k = 0; k < 8; k++) o[k] = f2bf(v[k]);
        *(bf16x8*)((u16*)p + i) = o;
    }
    static __device__ __forceinline__ u16 ldbf(const void* p, size_t i) {
        return ((const u16*)p)[i];
    }
    static __device__ __forceinline__ sh8 afrag(const void* p, size_t i) {
        return *(const sh8*)((const u16*)p + i);
    }
};
template<> struct IO<1> {
    static __device__ __forceinline__ float ld1(const void* p, size_t i) {
        return ((const float*)p)[i];
    }
    static __device__ __forceinline__ void ld8(const void* p, size_t i, float* o) {
        f32x4 a = *(const f32x4*)((const float*)p + i);
        f32x4 b = *(const f32x4*)((const float*)p + i + 4);
#pragma unroll
        for (int k = 0; k < 4; k++) { o[k] = a[k]; o[4 + k] = b[k]; }
    }
    static __device__ __forceinline__ void st8(void* p, size_t i, const float* v) {
        f32x4 a, b;
#pragma unroll
        for (int k = 0; k < 4; k++) { a[k] = v[k]; b[k] = v[4 + k]; }
        *(f32x4*)((float*)p + i) = a;
        *(f32x4*)((float*)p + i + 4) = b;
    }
    static __device__ __forceinline__ u16 ldbf(const void* p, size_t i) {
        return f2bf(((const float*)p)[i]);
    }
    static __device__ __forceinline__ sh8 afrag(const void* p, size_t i) {
        f32x4 a = *(const f32x4*)((const float*)p + i);
        f32x4 b = *(const f32x4*)((const float*)p + i + 4);
        sh8 r;
#pragma unroll
        for (int k = 0; k < 4; k++) {
            r[k]     = (short)f2bf(a[k]);
            r[4 + k] = (short)f2bf(b[k]);
        }
        return r;
    }
};

// ---------------------------------------------------------------------------
// Detector (validated in R2): fp32 bit-patterns read as bf16 contain huge/NaN
// values w.p. ~1; genuine bf16 N(0,1) stays |v|<6.  flag=1 -> fp32 buffers.
// ---------------------------------------------------------------------------
__global__ void k_detect(const u16* __restrict__ x, int* __restrict__ flag) {
    __shared__ int s;
    int t = threadIdx.x;
    if (t == 0) s = 0;
    __syncthreads();
    bool bad = false;
    for (int i = t; i < 4096; i += 256) {
        float v = bf2f(x[i]);
        if (!(fabsf(v) < 1e4f)) bad = true;   // catches NaN too
    }
    if (bad) s = 1;
    __syncthreads();
    if (t == 0) *flag = s;
}

// ---------------------------------------------------------------------------
// k_prep: WtT bf16 [144][2048] (B^T for the MFMA B-operand)
//   rows 0..63: selW[n=j>>3][:,s=j&7]; 64..127: upd[n][:,h];
//   128..135: mu[n][:]; 136..143: zeros
// ---------------------------------------------------------------------------
template<int DT>
__device__ __forceinline__ void prep_body(const void* selW, const void* upd,
                                          const void* mu, u16* __restrict__ WtT) {
    int idx = blockIdx.x * 256 + threadIdx.x;   // 144*256 threads
    int j = idx >> 8, d0 = (idx & 255) * 8;
    bf16x8 v;
    if (j < 64) {
        int n = j >> 3, s = j & 7;
#pragma unroll
        for (int i = 0; i < 8; i++) v[i] = IO<DT>::ldbf(selW, ((size_t)n * D + d0 + i) * 8 + s);
    } else if (j < 128) {
        int n = (j - 64) >> 3, h = j & 7;
#pragma unroll
        for (int i = 0; i < 8; i++) v[i] = IO<DT>::ldbf(upd, ((size_t)n * D + d0 + i) * 8 + h);
    } else if (j < 136) {
#pragma unroll
        for (int i = 0; i < 8; i++) v[i] = IO<DT>::ldbf(mu, (size_t)(j - 128) * D + d0 + i);
    } else {
#pragma unroll
        for (int i = 0; i < 8; i++) v[i] = 0;
    }
    *(bf16x8*)(WtT + (size_t)j * D + d0) = v;
}
__global__ void k_prep(const void* selW, const void* upd, const void* mu,
                       u16* WtT, const int* flag) {
    if (*flag) prep_body<1>(selW, upd, mu, WtT); else prep_body<0>(selW, upd, mu, WtT);
}

// ---------------------------------------------------------------------------
// k_consts: off[n][s]=W.mu, mu2[n]=|mu|^2, ub[n][h]=upd.debias  (all fp32)
// ---------------------------------------------------------------------------
template<int DT>
__device__ __forceinline__ void consts_body(const void* W, const void* mu,
                                            const void* upd, const void* deb,
                                            float* gOff, float* gMu2, float* gUb) {
    int n = blockIdx.x, t = threadIdx.x;
    float o[8] = {}, u[8] = {};
    float m2 = 0.f;
    for (int d = t; d < D; d += 256) {
        float mud = IO<DT>::ld1(mu,  (size_t)n * D + d);
        float dbd = IO<DT>::ld1(deb, (size_t)n * D + d);
        m2 += mud * mud;
        float wv[8], uv[8];
        IO<DT>::ld8(W,   ((size_t)n * D + d) * 8, wv);
        IO<DT>::ld8(upd, ((size_t)n * D + d) * 8, uv);
#pragma unroll
        for (int s = 0; s < 8; s++) {
            o[s] += wv[s] * mud;
            u[s] += uv[s] * dbd;
        }
    }
#pragma unroll
    for (int i = 1; i < 64; i <<= 1) {
        m2 += __shfl_xor(m2, i, 64);
#pragma unroll
        for (int s = 0; s < 8; s++) {
            o[s] += __shfl_xor(o[s], i, 64);
            u[s] += __shfl_xor(u[s], i, 64);
        }
    }
    __shared__ float red[4][17];
    int wave = t >> 6, lane = t & 63;
    if (lane == 0) {
        red[wave][0] = m2;
#pragma unroll
        for (int s = 0; s < 8; s++) { red[wave][1 + s] = o[s]; red[wave][9 + s] = u[s]; }
    }
    __syncthreads();
    if (t == 0) {
        float acc[17];
#pragma unroll
        for (int i = 0; i < 17; i++)
            acc[i] = red[0][i] + red[1][i] + red[2][i] + red[3][i];
        gMu2[n] = acc[0];
#pragma unroll
        for (int s = 0; s < 8; s++) { gOff[n * 8 + s] = acc[1 + s]; gUb[n * 8 + s] = acc[9 + s]; }
    }
}
__global__ void k_consts(const void* W, const void* mu, const void* upd, const void* deb,
                         float* gOff, float* gMu2, float* gUb, const int* flag) {
    if (*flag) consts_body<1>(W, mu, upd, deb, gOff, gMu2, gUb);
    else       consts_body<0>(W, mu, upd, deb, gOff, gMu2, gUb);
}

// ---------------------------------------------------------------------------
// k_gemm: P[tok][144] = X[4096][2048] * WtT^T via bf16 MFMA 16x16x32.
// Grid (32, 8): blocks of 128 tokens x K-split 8 (KR=256). 4 waves/block;
// wave = 32 tokens (2 m-subtiles of 16) x 144 cols (9 col-tiles).
// A-frag: lane l holds X[tok + (l&15)][k + (l>>4)*8 ..+8]   (fp32->bf16 cvt)
// B-frag: lane l holds WtT[ct*16 + (l&15)][k + (l>>4)*8 ..+8]
// C/D   : row(token) = (l>>4)*4 + reg, col = l&15   [m89/m91 verified]
// B-frags loaded once per K-chunk, reused across both m-subtiles.
// ---------------------------------------------------------------------------
template<int DT>
__device__ __forceinline__ void gemm_body(const void* X, const u16* __restrict__ WtT,
                                          float* __restrict__ P, int nparts) {
    const int t = threadIdx.x;
    const int w = t >> 6, l = t & 63;
    const int m = l & 15, q = l >> 4;
    const int tokw = blockIdx.x * 128 + w * 32;
    const int k0 = blockIdx.y * KR;

    const size_t aoff0 = (size_t)(tokw + m) * D + k0 + q * 8;
    const size_t aoff1 = aoff0 + (size_t)16 * D;
    const u16* bp = WtT + (size_t)m * D + k0 + q * 8;

    f32x4 acc[2][9];
#pragma unroll
    for (int s = 0; s < 2; s++)
#pragma unroll
        for (int ct = 0; ct < 9; ct++) acc[s][ct] = (f32x4){0.f, 0.f, 0.f, 0.f};

#pragma unroll 4
    for (int ks = 0; ks < KR / 32; ks++) {
        sh8 b[9];
#pragma unroll
        for (int ct = 0; ct < 9; ct++)
            b[ct] = *(const sh8*)(bp + (size_t)ct * 16 * D + ks * 32);
        sh8 a0 = IO<DT>::afrag(X, aoff0 + ks * 32);
        sh8 a1 = IO<DT>::afrag(X, aoff1 + ks * 32);
#pragma unroll
        for (int ct = 0; ct < 9; ct++)
            acc[0][ct] = __builtin_amdgcn_mfma_f32_16x16x32_bf16(a0, b[ct], acc[0][ct], 0, 0, 0);
#pragma unroll
        for (int ct = 0; ct < 9; ct++)
            acc[1][ct] = __builtin_amdgcn_mfma_f32_16x16x32_bf16(a1, b[ct], acc[1][ct], 0, 0, 0);
    }

    float* pout = P + (nparts > 1 ? (size_t)blockIdx.y * BT * NCOL : 0);
#pragma unroll
    for (int s = 0; s < 2; s++)
#pragma unroll
        for (int ct = 0; ct < 9; ct++)
#pragma unroll
            for (int r = 0; r < 4; r++) {
                size_t addr = (size_t)(tokw + s * 16 + q * 4 + r) * NCOL + ct * 16 + m;
                if (nparts > 1) pout[addr] = acc[s][ct][r];
                else            atomicAdd(&pout[addr], acc[s][ct][r]);
            }
}
__global__ __launch_bounds__(256) void k_gemm(const void* X, const u16* WtT,
                                              float* P, int nparts, const int* flag) {
    if (*flag) gemm_body<1>(X, WtT, P, nparts); else gemm_body<0>(X, WtT, P, nparts);
}

// ---------------------------------------------------------------------------
// k_final: per-token. sumx2 (fp32 exact) -> gates from P cols (argmax over
// logits, one sigmoid) -> rank-8 reconstruction -> coalesced blend.
// ---------------------------------------------------------------------------
template<int DT>
__device__ __forceinline__ void final_body(
    const void* X, const float* __restrict__ P,
    const void* CENTER, const void* SLOPE,
    const void* DGN, const void* BIAS,
    const float* __restrict__ OFF, const float* __restrict__ MU2,
    const float* __restrict__ UB, void* OUT, int nparts) {
    const int tok = blockIdx.x, t = threadIdx.x;

    __shared__ float red[4];
    __shared__ float pc[NCOL];
    __shared__ float bcast[10];

    float xf[8];
    IO<DT>::ld8(X, (size_t)tok * D + t * 8, xf);

    float s2 = 0.f;
#pragma unroll
    for (int i = 0; i < 8; i++) s2 += xf[i] * xf[i];
#pragma unroll
    for (int i = 1; i < 64; i <<= 1) s2 += __shfl_xor(s2, i, 64);
    if ((t & 63) == 0) red[t >> 6] = s2;

    if (t < NCOL) {
        float v = P[(size_t)tok * NCOL + t];
        for (int p = 1; p < nparts; p++)
            v += P[((size_t)p * BT + tok) * NCOL + t];
        pc[t] = v;
    }
    __syncthreads();

    if (t == 0) {
        float sumx2 = red[0] + red[1] + red[2] + red[3];
        float zbest = -1e30f; int bi = 0;
        for (int n = 0; n < NC; n++) {
            float mdot = pc[128 + n];
            float norm2 = sumx2 - 2.f * mdot + MU2[n];
            float sc = 0.f;
#pragma unroll
            for (int s = 0; s < 8; s++) {
                float dg = pc[8 * n + s] - OFF[8 * n + s];
                sc += dg * dg;
            }
            sc /= norm2;
            float z = IO<DT>::ld1(SLOPE, n) * (sc - IO<DT>::ld1(CENTER, n));
            if (z > zbest) { zbest = z; bi = n; }   // sigmoid monotone; strict > == np first-max
        }
        bcast[0] = 1.f / (1.f + expf(-zbest));      // sel_scale
        bcast[1] = (float)bi;
#pragma unroll
        for (int h = 0; h < 8; h++)
            bcast[2 + h] = pc[64 + 8 * bi + h] - UB[bi * 8 + h];
    }
    __syncthreads();

    const float sval = bcast[0];
    const int c = (int)bcast[1];
    float mx[8];
#pragma unroll
    for (int h = 0; h < 8; h++) mx[h] = bcast[2 + h];

    float bv[8];
    IO<DT>::ld8(BIAS, (size_t)c * D + t * 8, bv);
    float ov[8];
#pragma unroll
    for (int i = 0; i < 8; i++) {
        float dv[8];
        IO<DT>::ld8(DGN, ((size_t)c * D + t * 8 + i) * 8, dv);
        float du = 0.f;
#pragma unroll
        for (int h = 0; h < 8; h++) du += dv[h] * mx[h];
        ov[i] = (1.f - sval) * xf[i] + sval * (bv[i] + du);   // ETA = 1.0
    }
    IO<DT>::st8(OUT, (size_t)tok * D + t * 8, ov);
}
__global__ __launch_bounds__(256) void k_final(
    const void* X, const float* P, const void* CENTER, const void* SLOPE,
    const void* DGN, const void* BIAS, const float* OFF, const float* MU2,
    const float* UB, void* OUT, int nparts, const int* flag) {
    if (*flag)
        final_body<1>(X, P, CENTER, SLOPE, DGN, BIAS, OFF, MU2, UB, OUT, nparts);
    else
        final_body<0>(X, P, CENTER, SLOPE, DGN, BIAS, OFF, MU2, UB, OUT, nparts);
}

// ---------------------------------------------------------------------------
extern "C" void kernel_launch(void* const* d_in, const int* in_sizes, int n_in,
                              void* d_out, int out_size, void* d_ws, size_t ws_size,
                              hipStream_t stream) {
    const void* x      = d_in[0];
    const void* selW   = d_in[1];
    const void* mu     = d_in[2];
    const void* center = d_in[3];
    const void* slope  = d_in[4];
    const void* upd    = d_in[5];
    const void* dgn    = d_in[6];
    const void* biasW  = d_in[7];
    const void* debW   = d_in[8];

    const size_t sliceB = (size_t)BT * NCOL * 4;              // 2.36 MB
    const size_t wtB    = (size_t)NCOL * D * 2;               // 576 KB
    const size_t need   = (size_t)KSPLIT * sliceB + wtB + 4096;
    const int nparts = (ws_size >= need) ? KSPLIT : 1;        // ws_size is call-invariant

    char* ws = (char*)d_ws;
    float* P   = (float*)ws;
    u16*   WtT = (u16*)(ws + (size_t)nparts * sliceB);
    float* off = (float*)(ws + (size_t)nparts * sliceB + wtB);
    float* mu2 = off + 64;
    float* ub  = mu2 + 8;
    int*   flag = (int*)(ub + 64);

    k_detect<<<1, 256, 0, stream>>>((const u16*)x, flag);
    if (nparts == 1)
        hipMemsetAsync(P, 0, sliceB, stream);                 // atomics need zeroed P
    k_prep  <<<NCOL, 256, 0, stream>>>(selW, upd, mu, WtT, flag);
    k_consts<<<NC, 256, 0, stream>>>(selW, mu, upd, debW, off, mu2, ub, flag);
    k_gemm  <<<dim3(BT / 128, KSPLIT), 256, 0, stream>>>(x, WtT, P, nparts, flag);
    k_final <<<BT, 256, 0, stream>>>(x, P, center, slope, dgn, biasW,
                                     off, mu2, ub, d_out, nparts, flag);
}

// Round 5
// 157.123 us; speedup vs baseline: 1.9547x; 1.0782x over previous
//
#include <hip/hip_runtime.h>
#include <math.h>

typedef unsigned short u16;
typedef unsigned int   u32;
typedef __attribute__((ext_vector_type(4))) unsigned short u16x4;
typedef __attribute__((ext_vector_type(8))) unsigned short bf16x8;
typedef __attribute__((ext_vector_type(8))) short sh8;      // MFMA A/B frag (8 bf16)
typedef __attribute__((ext_vector_type(4))) float f32x4;    // MFMA C/D frag

#define BT     4096
#define D      2048
#define NC     8
#define NCOL   144     // 64 selW + 64 upd + 8 mu + 8 zero-pad (9 MFMA col-tiles)
#define KSPLIT 8
#define KR     (D / KSPLIT)   // 256

__device__ __forceinline__ float bf2f(u16 v) {
    u32 u = ((u32)v) << 16;
    float f; __builtin_memcpy(&f, &u, 4); return f;
}
__device__ __forceinline__ u16 f2bf(float f) {
    u32 u; __builtin_memcpy(&u, &f, 4);
    u += 0x7fffu + ((u >> 16) & 1);        // RNE
    return (u16)(u >> 16);
}

// ---- dtype-polymorphic loads: DT=0 bf16 buffers, DT=1 fp32 buffers ----
template<int DT> struct IO;
template<> struct IO<0> {
    static __device__ __forceinline__ float ld1(const void* p, size_t i) {
        return bf2f(((const u16*)p)[i]);
    }
    static __device__ __forceinline__ void ld4(const void* p, size_t i, float* o) {
        u16x4 v = *(const u16x4*)((const u16*)p + i);
#pragma unroll
        for (int k = 0; k < 4; k++) o[k] = bf2f(v[k]);
    }
    static __device__ __forceinline__ void ld8(const void* p, size_t i, float* o) {
        bf16x8 v = *(const bf16x8*)((const u16*)p + i);
#pragma unroll
        for (int k = 0; k < 8; k++) o[k] = bf2f(v[k]);
    }
    static __device__ __forceinline__ void st4(void* p, size_t i, const float* v) {
        u16x4 o;
#pragma unroll
        for (int k = 0; k < 4; k++) o[k] = f2bf(v[k]);
        *(u16x4*)((u16*)p + i) = o;
    }
    static __device__ __forceinline__ u16 ldbf(const void* p, size_t i) {
        return ((const u16*)p)[i];
    }
    static __device__ __forceinline__ sh8 afrag(const void* p, size_t i) {
        return *(const sh8*)((const u16*)p + i);
    }
};
template<> struct IO<1> {
    static __device__ __forceinline__ float ld1(const void* p, size_t i) {
        return ((const float*)p)[i];
    }
    static __device__ __forceinline__ void ld4(const void* p, size_t i, float* o) {
        f32x4 a = *(const f32x4*)((const float*)p + i);
#pragma unroll
        for (int k = 0; k < 4; k++) o[k] = a[k];
    }
    static __device__ __forceinline__ void ld8(const void* p, size_t i, float* o) {
        f32x4 a = *(const f32x4*)((const float*)p + i);
        f32x4 b = *(const f32x4*)((const float*)p + i + 4);
#pragma unroll
        for (int k = 0; k < 4; k++) { o[k] = a[k]; o[4 + k] = b[k]; }
    }
    static __device__ __forceinline__ void st4(void* p, size_t i, const float* v) {
        f32x4 a;
#pragma unroll
        for (int k = 0; k < 4; k++) a[k] = v[k];
        *(f32x4*)((float*)p + i) = a;
    }
    static __device__ __forceinline__ u16 ldbf(const void* p, size_t i) {
        return f2bf(((const float*)p)[i]);
    }
    static __device__ __forceinline__ sh8 afrag(const void* p, size_t i) {
        f32x4 a = *(const f32x4*)((const float*)p + i);
        f32x4 b = *(const f32x4*)((const float*)p + i + 4);
        sh8 r;
#pragma unroll
        for (int k = 0; k < 4; k++) {
            r[k]     = (short)f2bf(a[k]);
            r[4 + k] = (short)f2bf(b[k]);
        }
        return r;
    }
};

// ---------------------------------------------------------------------------
// k_detect (validated R2/R3 A/B): fp32 bit-patterns read as bf16 give huge/NaN
// w.p. ~1. flag=1 -> fp32 buffers. Also zeroes the 136-float const table
// (off[64] | mu2[8] | ub[64]) so k_prep_consts can atomicAdd into it.
// ---------------------------------------------------------------------------
__global__ void k_detect(const u16* __restrict__ x, int* __restrict__ flag,
                         float* __restrict__ consts136) {
    __shared__ int s;
    int t = threadIdx.x;
    if (t == 0) s = 0;
    if (t < 136) consts136[t] = 0.f;
    __syncthreads();
    bool bad = false;
    for (int i = t; i < 4096; i += 256) {
        float v = bf2f(x[i]);
        if (!(fabsf(v) < 1e4f)) bad = true;   // catches NaN too
    }
    if (bad) s = 1;
    __syncthreads();
    if (t == 0) *flag = s;
}

// ---------------------------------------------------------------------------
// k_prep_consts: merged.
//  blocks 0..143: build WtT bf16 [144][2048] (B^T for MFMA B-operand)
//    rows 0..63 selW[n][:,s]; 64..127 upd[n][:,h]; 128..135 mu[n]; 136..143 0
//  blocks 144..207 (64 blocks = 8 concepts x 8 D-chunks of 256):
//    partial off/mu2/ub, block-reduced, atomicAdd into const table.
// ---------------------------------------------------------------------------
template<int DT>
__device__ __forceinline__ void prep_part(const void* selW, const void* upd,
                                          const void* mu, u16* __restrict__ WtT) {
    int idx = blockIdx.x * 256 + threadIdx.x;
    int j = idx >> 8, d0 = (idx & 255) * 8;
    bf16x8 v;
    if (j < 64) {
        int n = j >> 3, s = j & 7;
#pragma unroll
        for (int i = 0; i < 8; i++) v[i] = IO<DT>::ldbf(selW, ((size_t)n * D + d0 + i) * 8 + s);
    } else if (j < 128) {
        int n = (j - 64) >> 3, h = j & 7;
#pragma unroll
        for (int i = 0; i < 8; i++) v[i] = IO<DT>::ldbf(upd, ((size_t)n * D + d0 + i) * 8 + h);
    } else if (j < 136) {
#pragma unroll
        for (int i = 0; i < 8; i++) v[i] = IO<DT>::ldbf(mu, (size_t)(j - 128) * D + d0 + i);
    } else {
#pragma unroll
        for (int i = 0; i < 8; i++) v[i] = 0;
    }
    *(bf16x8*)(WtT + (size_t)j * D + d0) = v;
}

template<int DT>
__device__ __forceinline__ void consts_part(const void* W, const void* mu,
                                            const void* upd, const void* deb,
                                            float* gOff, float* gMu2, float* gUb) {
    int bid = blockIdx.x - 144;
    int n = bid >> 3, t = threadIdx.x;
    int d = (bid & 7) * 256 + t;

    float mud = IO<DT>::ld1(mu,  (size_t)n * D + d);
    float dbd = IO<DT>::ld1(deb, (size_t)n * D + d);
    float m2 = mud * mud;
    float wv[8], uv[8], o[8], u[8];
    IO<DT>::ld8(W,   ((size_t)n * D + d) * 8, wv);
    IO<DT>::ld8(upd, ((size_t)n * D + d) * 8, uv);
#pragma unroll
    for (int s = 0; s < 8; s++) { o[s] = wv[s] * mud; u[s] = uv[s] * dbd; }

#pragma unroll
    for (int i = 1; i < 64; i <<= 1) {
        m2 += __shfl_xor(m2, i, 64);
#pragma unroll
        for (int s = 0; s < 8; s++) {
            o[s] += __shfl_xor(o[s], i, 64);
            u[s] += __shfl_xor(u[s], i, 64);
        }
    }
    __shared__ float red[4][17];
    int wave = t >> 6, lane = t & 63;
    if (lane == 0) {
        red[wave][0] = m2;
#pragma unroll
        for (int s = 0; s < 8; s++) { red[wave][1 + s] = o[s]; red[wave][9 + s] = u[s]; }
    }
    __syncthreads();
    if (t < 17) {
        float acc = red[0][t] + red[1][t] + red[2][t] + red[3][t];
        if (t == 0)      atomicAdd(&gMu2[n], acc);
        else if (t < 9)  atomicAdd(&gOff[n * 8 + t - 1], acc);
        else             atomicAdd(&gUb[n * 8 + t - 9], acc);
    }
}

__global__ __launch_bounds__(256) void k_prep_consts(
    const void* selW, const void* upd, const void* mu, const void* deb,
    u16* WtT, float* gOff, float* gMu2, float* gUb, const int* flag) {
    int f = *flag;
    if (blockIdx.x < 144) {
        if (f) prep_part<1>(selW, upd, mu, WtT); else prep_part<0>(selW, upd, mu, WtT);
    } else {
        if (f) consts_part<1>(selW, mu, upd, deb, gOff, gMu2, gUb);
        else   consts_part<0>(selW, mu, upd, deb, gOff, gMu2, gUb);
    }
}

// ---------------------------------------------------------------------------
// k_gemm: P[tok][144] = X * WtT^T via bf16 MFMA 16x16x32 (unchanged from R4).
// ---------------------------------------------------------------------------
template<int DT>
__device__ __forceinline__ void gemm_body(const void* X, const u16* __restrict__ WtT,
                                          float* __restrict__ P, int nparts) {
    const int t = threadIdx.x;
    const int w = t >> 6, l = t & 63;
    const int m = l & 15, q = l >> 4;
    const int tokw = blockIdx.x * 128 + w * 32;
    const int k0 = blockIdx.y * KR;

    const size_t aoff0 = (size_t)(tokw + m) * D + k0 + q * 8;
    const size_t aoff1 = aoff0 + (size_t)16 * D;
    const u16* bp = WtT + (size_t)m * D + k0 + q * 8;

    f32x4 acc[2][9];
#pragma unroll
    for (int s = 0; s < 2; s++)
#pragma unroll
        for (int ct = 0; ct < 9; ct++) acc[s][ct] = (f32x4){0.f, 0.f, 0.f, 0.f};

#pragma unroll 4
    for (int ks = 0; ks < KR / 32; ks++) {
        sh8 b[9];
#pragma unroll
        for (int ct = 0; ct < 9; ct++)
            b[ct] = *(const sh8*)(bp + (size_t)ct * 16 * D + ks * 32);
        sh8 a0 = IO<DT>::afrag(X, aoff0 + ks * 32);
        sh8 a1 = IO<DT>::afrag(X, aoff1 + ks * 32);
#pragma unroll
        for (int ct = 0; ct < 9; ct++)
            acc[0][ct] = __builtin_amdgcn_mfma_f32_16x16x32_bf16(a0, b[ct], acc[0][ct], 0, 0, 0);
#pragma unroll
        for (int ct = 0; ct < 9; ct++)
            acc[1][ct] = __builtin_amdgcn_mfma_f32_16x16x32_bf16(a1, b[ct], acc[1][ct], 0, 0, 0);
    }

    float* pout = P + (nparts > 1 ? (size_t)blockIdx.y * BT * NCOL : 0);
#pragma unroll
    for (int s = 0; s < 2; s++)
#pragma unroll
        for (int ct = 0; ct < 9; ct++)
#pragma unroll
            for (int r = 0; r < 4; r++) {
                size_t addr = (size_t)(tokw + s * 16 + q * 4 + r) * NCOL + ct * 16 + m;
                if (nparts > 1) pout[addr] = acc[s][ct][r];
                else            atomicAdd(&pout[addr], acc[s][ct][r]);
            }
}
__global__ __launch_bounds__(256) void k_gemm(const void* X, const u16* WtT,
                                              float* P, int nparts, const int* flag) {
    if (*flag) gemm_body<1>(X, WtT, P, nparts); else gemm_body<0>(X, WtT, P, nparts);
}

// ---------------------------------------------------------------------------
// k_final v2: wave-per-token, ZERO barriers. 4 waves/block, grid 1024.
// Interleaved mapping: lane l, chunk j -> d = j*256 + l*4 (coalesced 1KB/instr)
// Gate: lanes 0..7 compute concept logits in parallel; 3-step shuffle
// butterfly argmax (first-max tie-break == np.argmax); shuffle broadcasts.
// ---------------------------------------------------------------------------
template<int DT>
__device__ __forceinline__ void final_body(
    const void* X, const float* __restrict__ P,
    const void* CENTER, const void* SLOPE,
    const void* DGN, const void* BIAS,
    const float* __restrict__ OFF, const float* __restrict__ MU2,
    const float* __restrict__ UB, void* OUT, int nparts) {
    const int w = threadIdx.x >> 6, l = threadIdx.x & 63;
    const int tok = blockIdx.x * 4 + w;

    // ---- load X, sumx2 ----
    float xf[8][4];
    float s2 = 0.f;
#pragma unroll
    for (int j = 0; j < 8; j++) {
        IO<DT>::ld4(X, (size_t)tok * D + j * 256 + l * 4, xf[j]);
#pragma unroll
        for (int i = 0; i < 4; i++) s2 += xf[j][i] * xf[j][i];
    }
#pragma unroll
    for (int i = 1; i < 64; i <<= 1) s2 += __shfl_xor(s2, i, 64);

    // ---- gate logits on lanes 0..7 ----
    float zv = -1e30f;
    int   iv = l;
    if (l < NC) {
        int n = l;
        float pcv[8], mdot = 0.f;
#pragma unroll
        for (int s = 0; s < 8; s++) pcv[s] = 0.f;
        for (int p = 0; p < nparts; p++) {
            const float* pr = P + ((size_t)p * BT + tok) * NCOL;
#pragma unroll
            for (int s = 0; s < 8; s++) pcv[s] += pr[8 * n + s];
            mdot += pr[128 + n];
        }
        float norm2 = s2 - 2.f * mdot + MU2[n];
        float sc = 0.f;
#pragma unroll
        for (int s = 0; s < 8; s++) {
            float dg = pcv[s] - OFF[8 * n + s];
            sc += dg * dg;
        }
        sc /= norm2;
        zv = IO<DT>::ld1(SLOPE, n) * (sc - IO<DT>::ld1(CENTER, n));
    }
    // butterfly argmax over lanes 0..7 (partners stay within 0..7)
#pragma unroll
    for (int i = 1; i < 8; i <<= 1) {
        float z2 = __shfl_xor(zv, i, 64);
        int   i2 = __shfl_xor(iv, i, 64);
        if (z2 > zv || (z2 == zv && i2 < iv)) { zv = z2; iv = i2; }
    }
    const float zbest = __shfl(zv, 0, 64);
    const int   c     = __shfl(iv, 0, 64);
    const float sval  = 1.f / (1.f + expf(-zbest));

    // ---- mx[h] = P[tok][64+8c+h] - ub ----
    float v = 0.f;
    if (l < 8) {
        for (int p = 0; p < nparts; p++)
            v += P[((size_t)p * BT + tok) * NCOL + 64 + 8 * c + l];
        v -= UB[c * 8 + l];
    }
    float mx[8];
#pragma unroll
    for (int h = 0; h < 8; h++) mx[h] = __shfl(v, h, 64);

    // ---- blend ----
#pragma unroll
    for (int j = 0; j < 8; j++) {
        float bv[4], ov[4];
        IO<DT>::ld4(BIAS, (size_t)c * D + j * 256 + l * 4, bv);
#pragma unroll
        for (int i = 0; i < 4; i++) {
            float dv[8];
            IO<DT>::ld8(DGN, ((size_t)c * D + j * 256 + l * 4 + i) * 8, dv);
            float du = 0.f;
#pragma unroll
            for (int h = 0; h < 8; h++) du += dv[h] * mx[h];
            ov[i] = (1.f - sval) * xf[j][i] + sval * (bv[i] + du);   // ETA = 1.0
        }
        IO<DT>::st4(OUT, (size_t)tok * D + j * 256 + l * 4, ov);
    }
}
__global__ __launch_bounds__(256) void k_final(
    const void* X, const float* P, const void* CENTER, const void* SLOPE,
    const void* DGN, const void* BIAS, const float* OFF, const float* MU2,
    const float* UB, void* OUT, int nparts, const int* flag) {
    if (*flag)
        final_body<1>(X, P, CENTER, SLOPE, DGN, BIAS, OFF, MU2, UB, OUT, nparts);
    else
        final_body<0>(X, P, CENTER, SLOPE, DGN, BIAS, OFF, MU2, UB, OUT, nparts);
}

// ---------------------------------------------------------------------------
extern "C" void kernel_launch(void* const* d_in, const int* in_sizes, int n_in,
                              void* d_out, int out_size, void* d_ws, size_t ws_size,
                              hipStream_t stream) {
    const void* x      = d_in[0];
    const void* selW   = d_in[1];
    const void* mu     = d_in[2];
    const void* center = d_in[3];
    const void* slope  = d_in[4];
    const void* upd    = d_in[5];
    const void* dgn    = d_in[6];
    const void* biasW  = d_in[7];
    const void* debW   = d_in[8];

    const size_t sliceB = (size_t)BT * NCOL * 4;              // 2.36 MB
    const size_t wtB    = (size_t)NCOL * D * 2;               // 576 KB
    const size_t need   = (size_t)KSPLIT * sliceB + wtB + 4096;
    const int nparts = (ws_size >= need) ? KSPLIT : 1;        // ws_size is call-invariant

    char* ws = (char*)d_ws;
    float* P   = (float*)ws;
    u16*   WtT = (u16*)(ws + (size_t)nparts * sliceB);
    float* off = (float*)(ws + (size_t)nparts * sliceB + wtB);
    float* mu2 = off + 64;
    float* ub  = mu2 + 8;
    int*   flag = (int*)(ub + 64);

    k_detect<<<1, 256, 0, stream>>>((const u16*)x, flag, off);
    if (nparts == 1)
        hipMemsetAsync(P, 0, sliceB, stream);                 // atomics need zeroed P
    k_prep_consts<<<144 + 64, 256, 0, stream>>>(selW, upd, mu, debW,
                                                WtT, off, mu2, ub, flag);
    k_gemm <<<dim3(BT / 128, KSPLIT), 256, 0, stream>>>(x, WtT, P, nparts, flag);
    k_final<<<BT / 4, 256, 0, stream>>>(x, P, center, slope, dgn, biasW,
                                        off, mu2, ub, d_out, nparts, flag);
}